// Round 8
// baseline (513.829 us; speedup 1.0000x reference)
//
#include <hip/hip_runtime.h>

typedef unsigned short ush;
typedef unsigned int uint32;
typedef __attribute__((ext_vector_type(8))) __bf16 bf16x8;
typedef __attribute__((ext_vector_type(4))) float f32x4;

#define NBLK 256
#define RB   4     // batch rows per block
#define NTHR 512
#define SENC 256
#define TDEC 512
#define HDIM 128
#define HSTR 144   // h row stride (ush): 72 dw ≡ 8 mod 32 -> replicated reads/writes 2-way (free)
#define XSTR 520   // x row stride (ush)
#define PSTR 1024  // pred row stride (ush)

#define LOG2E  1.4426950408889634f
#define LOG2E2 2.8853900817779268f

__device__ __forceinline__ float bf2f(ush u){
  uint32 v = ((uint32)u) << 16;
  return __builtin_bit_cast(float, v);
}
__device__ __forceinline__ ush f2bf(float f){            // RNE
  uint32 u = __builtin_bit_cast(uint32, f);
  u = (u + 0x7FFFu + ((u >> 16) & 1u)) >> 16;
  return (ush)u;
}
__device__ __forceinline__ float lo16f(uint32 w){ return __builtin_bit_cast(float, w << 16); }
__device__ __forceinline__ float hi16f(uint32 w){ return __builtin_bit_cast(float, w & 0xFFFF0000u); }

__device__ __forceinline__ float loadf(const void* p, int i, bool f32){
  return f32 ? ((const float*)p)[i] : bf2f(((const ush*)p)[i]);
}
// raw bf16 fragment load: bit-exact copy of harness weights for bf16 inputs
__device__ __forceinline__ bf16x8 load8bf(const void* p, int i, bool f32){
  bf16x8 r;
  if (!f32){
    uint4 u = *reinterpret_cast<const uint4*>((const ush*)p + i);
    r = __builtin_bit_cast(bf16x8, u);
  } else {
    const float* fp = (const float*)p + i;
    #pragma unroll
    for (int j = 0; j < 8; ++j) r[j] = (__bf16)fp[j];
  }
  return r;
}
__device__ __forceinline__ float sigm(float x){
  return __builtin_amdgcn_rcpf(1.0f + __builtin_amdgcn_exp2f(-x * LOG2E));
}
__device__ __forceinline__ float tnh(float x){
  return 1.0f - 2.0f * __builtin_amdgcn_rcpf(__builtin_amdgcn_exp2f(x * LOG2E2) + 1.0f);
}
__device__ __forceinline__ f32x4 mfma4(const bf16x8* af, const bf16x8* b, f32x4 c){
  f32x4 r = __builtin_amdgcn_mfma_f32_16x16x32_bf16(af[0], b[0], c, 0, 0, 0);
  r = __builtin_amdgcn_mfma_f32_16x16x32_bf16(af[1], b[1], r, 0, 0, 0);
  r = __builtin_amdgcn_mfma_f32_16x16x32_bf16(af[2], b[2], r, 0, 0, 0);
  r = __builtin_amdgcn_mfma_f32_16x16x32_bf16(af[3], b[3], r, 0, 0, 0);
  return r;
}
// full-rate DPP cross-lane add (VALU pipe, no LDS/bpermute latency)
template<int CTRL>
__device__ __forceinline__ float dpp_add(float x){
  int yi = __builtin_amdgcn_update_dpp(0, __builtin_bit_cast(int, x), CTRL, 0xF, 0xF, true);
  return x + __builtin_bit_cast(float, yi);
}
// sum across the 16 lanes of each DPP row (= our (q, n=0..15) groups):
// quad_perm xor1 (0xB1), quad_perm xor2 (0x4E), row_mirror (0x140), row_ror:8 (0x128)
__device__ __forceinline__ void rowsum16(float& a, float& b){
  a = dpp_add<0xB1>(a);  b = dpp_add<0xB1>(b);
  a = dpp_add<0x4E>(a);  b = dpp_add<0x4E>(b);
  a = dpp_add<0x140>(a); b = dpp_add<0x140>(b);
  a = dpp_add<0x128>(a); b = dpp_add<0x128>(b);
}

// 256 blocks x 4 batch rows, 8 waves/block; wave w owns hidden cols [16w,16w+16).
// A-ROW REPLICATION: A[m] = h[m>>2] -> C[4q+r][n] = gates[q][n] in every reg.
// Bias rides as the C operand of the first MFMA. NO pred MFMA tile: pred is
// computed from the previous step's f32 hv via per-lane wfc products + 4
// full-rate DPP row-adds + one 2-float LDS partial per (row,wave); the next
// step sums the 8 wave-partials post-barrier (4x broadcast ds_read_b128, in
// the MFMA shadow). Decode: 16 MFMAs/wave (was 20), no pred-chain head
// latency. Partial buffer double-buffered (race-free). One barrier per step.
__global__ void __launch_bounds__(NTHR, 2)
lstm_kernel(const void* __restrict__ xg,  const void* __restrict__ wih,
            const void* __restrict__ whh, const void* __restrict__ bih,
            const void* __restrict__ bhh, const void* __restrict__ wfc,
            const void* __restrict__ bfc, void* __restrict__ outg)
{
  __shared__ __attribute__((aligned(16))) ush   x_lds[RB * XSTR];      // [row][t*2+c]
  __shared__ __attribute__((aligned(16))) ush   h_lds[2][RB * HSTR];   // [buf][row][j]
  __shared__ __attribute__((aligned(16))) ush   pred_lds[RB][PSTR];    // [row][d*2+o]
  __shared__ __attribute__((aligned(16))) float part_lds[2][RB][8][2]; // [buf][q][wave][o]

  const int tid   = threadIdx.x;
  const int lane  = tid & 63;
  const int wv    = tid >> 6;
  const int n     = lane & 15;   // MFMA col index within tile (= A-row m)
  const int q     = lane >> 4;   // quad; this lane's batch row
  const int gbase = wv << 4;
  const int blk   = blockIdx.x;

  // runtime storage-dtype detection (bf16 vs f32) from w_hh bit patterns
  const uint32* wp = (const uint32*)whh;
  int cnt = 0;
  #pragma unroll
  for (int i = 0; i < 64; ++i){
    uint32 e = (wp[i] >> 7) & 0xFFu;
    cnt += (e >= 90u && e <= 140u) ? 1 : 0;
  }
  const bool isf32 = (cnt < 40);

  for (int i = tid; i < 2 * RB * HSTR; i += NTHR) h_lds[0][i] = 0;  // both bufs

  // stage this block's 4 encoder rows into LDS as bf16: [row][t*2+c]
  if (!isf32){
    if (tid < 256){
      int row = tid >> 6, c = (tid & 63) * 8;
      uint4 v = *reinterpret_cast<const uint4*>((const ush*)xg + (blk * RB + row) * (SENC * 2) + c);
      *reinterpret_cast<uint4*>(&x_lds[row * XSTR + c]) = v;
    }
  } else {
    for (int i = tid; i < RB * SENC * 2; i += NTHR){
      int row = i >> 9, c = i & 511;
      x_lds[row * XSTR + c] = f2bf(((const float*)xg)[(blk * RB + row) * (SENC * 2) + c]);
    }
  }

  // ---- loop-invariant preloads: weights RAW (bit-exact for bf16) ----
  float wih0v[4], wih1v[4];
  f32x4 biasC[4];    // broadcast bias, used as C operand of first MFMA
  bf16x8 bfr[4][4];  // [gate p][kk]: B[k][g]=Whh[g][k], k=kk*32+q*8+j, g=p*128+gbase+n
  #pragma unroll
  for (int p = 0; p < 4; ++p){
    int g = p * 128 + gbase + n;
    float b = loadf(bih, g, isf32) + loadf(bhh, g, isf32);
    biasC[p][0] = b; biasC[p][1] = b; biasC[p][2] = b; biasC[p][3] = b;
    wih0v[p] = loadf(wih, g * 2 + 0, isf32);
    wih1v[p] = loadf(wih, g * 2 + 1, isf32);
    #pragma unroll
    for (int kk = 0; kk < 4; ++kk)
      bfr[p][kk] = load8bf(whh, g * HDIM + kk * 32 + q * 8, isf32);
  }
  // per-lane wfc weights for the DPP pred reduction + bias scalars
  const float wfc0n = loadf(wfc, gbase + n, isf32);          // wfc[0][col]
  const float wfc1n = loadf(wfc, HDIM + gbase + n, isf32);   // wfc[1][col]
  const float pb0   = loadf(bfc, 0, isf32);
  const float pb1   = loadf(bfc, 1, isf32);

  float cc = 0.0f;                   // c-state for (row q, col gbase+n)
  const int arow  = (n >> 2) * HSTR; // replicated A-row base: A[m]=h[m>>2]
  const int hwofs = q * HSTR + gbase + n;  // this lane's h-write offset
  int cur = 0;

  __syncthreads();

  // -------- encoder s=0..SENC-1, plus peeled first decoder cell s==SENC ----
  #pragma unroll 1
  for (int s = 0; s <= SENC; ++s){
    int t = (s < SENC) ? s : SENC - 1;   // s==SENC: inp0 = x[:,-1,:]
    uint32 xw = *reinterpret_cast<const uint32*>(&x_lds[q * XSTR + t * 2]);
    float xa = lo16f(xw), xb = hi16f(xw);

    const ush* hb = &h_lds[cur][arow];
    bf16x8 af[4];
    #pragma unroll
    for (int kk = 0; kk < 4; ++kk)
      af[kk] = *reinterpret_cast<const bf16x8*>(hb + kk * 32 + q * 8);

    f32x4 acc0 = mfma4(af, bfr[0], biasC[0]);
    f32x4 acc1 = mfma4(af, bfr[1], biasC[1]);
    float g0 = acc0[0] + wih0v[0] * xa + wih1v[0] * xb;
    float si = sigm(g0);
    f32x4 acc2 = mfma4(af, bfr[2], biasC[2]);
    float g1 = acc1[0] + wih0v[1] * xa + wih1v[1] * xb;
    float sf = sigm(g1);
    f32x4 acc3 = mfma4(af, bfr[3], biasC[3]);
    float g2 = acc2[0] + wih0v[2] * xa + wih1v[2] * xb;
    float tg = tnh(g2);
    cc = sf * cc + si * tg;
    float th = tnh(cc);
    float g3 = acc3[0] + wih0v[3] * xa + wih1v[3] * xb;
    float so = sigm(g3);
    float hv = so * th;
    h_lds[cur ^ 1][hwofs] = f2bf(hv);

    if (s == SENC){
      // emit pred partials of h_dec1 (f32, pre-rounding) for decode iter 0
      float u0 = hv * wfc0n, u1 = hv * wfc1n;
      rowsum16(u0, u1);
      if (n == 0)
        *reinterpret_cast<float2*>(&part_lds[cur ^ 1][q][wv][0]) = make_float2(u0, u1);
    }

    __syncthreads();
    cur ^= 1;
  }

  // ---------------- decoder: pure h-recurrence + pred feedback --------------
  #pragma unroll 1
  for (int d = 0; d < TDEC - 1; ++d){
    // reconstruct pred_d = wfc . h_{d-1} + bfc from the 8 wave-partials
    const float4* pp = reinterpret_cast<const float4*>(&part_lds[cur][q][0][0]);
    float4 r0 = pp[0], r1 = pp[1], r2 = pp[2], r3 = pp[3];
    float p0 = ((r0.x + r0.z) + (r1.x + r1.z)) + ((r2.x + r2.z) + (r3.x + r3.z)) + pb0;
    float p1 = ((r0.y + r0.w) + (r1.y + r1.w)) + ((r2.y + r2.w) + (r3.y + r3.w)) + pb1;

    const ush* hb = &h_lds[cur][arow];
    bf16x8 af[4];
    #pragma unroll
    for (int kk = 0; kk < 4; ++kk)
      af[kk] = *reinterpret_cast<const bf16x8*>(hb + kk * 32 + q * 8);

    f32x4 acc0 = mfma4(af, bfr[0], biasC[0]);
    f32x4 acc1 = mfma4(af, bfr[1], biasC[1]);
    float g0 = acc0[0] + wih0v[0] * p0 + wih1v[0] * p1;
    float si = sigm(g0);
    f32x4 acc2 = mfma4(af, bfr[2], biasC[2]);
    float g1 = acc1[0] + wih0v[1] * p0 + wih1v[1] * p1;
    float sf = sigm(g1);
    f32x4 acc3 = mfma4(af, bfr[3], biasC[3]);
    float g2 = acc2[0] + wih0v[2] * p0 + wih1v[2] * p1;
    float tg = tnh(g2);
    cc = sf * cc + si * tg;
    float th = tnh(cc);
    float g3 = acc3[0] + wih0v[3] * p0 + wih1v[3] * p1;
    float so = sigm(g3);
    float hv = so * th;
    h_lds[cur ^ 1][hwofs] = f2bf(hv);

    // emit pred partials for step d+1 (from f32 hv)
    float u0 = hv * wfc0n, u1 = hv * wfc1n;
    rowsum16(u0, u1);
    if (n == 0)
      *reinterpret_cast<float2*>(&part_lds[cur ^ 1][q][wv][0]) = make_float2(u0, u1);

    // store output pred_d (reconstructed this iteration)
    if (wv == 0 && n < 2)
      pred_lds[q][d * 2 + n] = f2bf(n ? p1 : p0);

    __syncthreads();
    cur ^= 1;
  }

  // epilogue: preds[511] from the partials emitted at d=510
  {
    const float4* pp = reinterpret_cast<const float4*>(&part_lds[cur][q][0][0]);
    float4 r0 = pp[0], r1 = pp[1], r2 = pp[2], r3 = pp[3];
    float p0 = ((r0.x + r0.z) + (r1.x + r1.z)) + ((r2.x + r2.z) + (r3.x + r3.z)) + pb0;
    float p1 = ((r0.y + r0.w) + (r1.y + r1.w)) + ((r2.y + r2.w) + (r3.y + r3.w)) + pb1;
    if (wv == 0 && n < 2)
      pred_lds[q][(TDEC - 1) * 2 + n] = f2bf(n ? p1 : p0);
  }
  __syncthreads();

  // bulk coalesced output write: 4 rows x 1024 ush per block
  if (!isf32){
    int row = tid >> 7, c = (tid & 127) * 8;  // 512 threads x uint4
    uint4 v = *reinterpret_cast<const uint4*>(&pred_lds[row][c]);
    *reinterpret_cast<uint4*>((ush*)outg + (blk * RB + row) * (TDEC * 2) + c) = v;
  } else {
    for (int i = tid; i < RB * TDEC * 2; i += NTHR){
      int row = i >> 10, c = i & 1023;
      ((float*)outg)[(blk * RB + row) * (TDEC * 2) + c] = bf2f(pred_lds[row][c]);
    }
  }
}

extern "C" void kernel_launch(void* const* d_in, const int* in_sizes, int n_in,
                              void* d_out, int out_size, void* d_ws, size_t ws_size,
                              hipStream_t stream) {
  lstm_kernel<<<dim3(NBLK), dim3(NTHR), 0, stream>>>(
      d_in[0], d_in[1], d_in[2], d_in[3], d_in[4], d_in[5], d_in[6], d_out);
}

// Round 9
// 444.152 us; speedup vs baseline: 1.1569x; 1.1569x over previous
//
#include <hip/hip_runtime.h>

typedef unsigned short ush;
typedef unsigned int uint32;
typedef __attribute__((ext_vector_type(8))) __bf16 bf16x8;
typedef __attribute__((ext_vector_type(4))) float f32x4;

#define NBLK 256
#define RB   4     // batch rows per block
#define NTHR 512
#define SENC 256
#define TDEC 512
#define HDIM 128
#define HSTR 144   // h row stride (ush): 72 dw ≡ 8 mod 32 -> replicated reads/writes 2-way (free)
#define XSTR 520   // x row stride (ush)
#define PSTR 1024  // pred row stride (ush)

#define LOG2E  1.4426950408889634f
#define LOG2E2 2.8853900817779268f

__device__ __forceinline__ float bf2f(ush u){
  uint32 v = ((uint32)u) << 16;
  return __builtin_bit_cast(float, v);
}
__device__ __forceinline__ ush f2bf(float f){            // RNE (manual; preload path)
  uint32 u = __builtin_bit_cast(uint32, f);
  u = (u + 0x7FFFu + ((u >> 16) & 1u)) >> 16;
  return (ush)u;
}
// hot-path RNE convert: single v_cvt op on gfx950, same rounding as f2bf
__device__ __forceinline__ ush f2bf_hw(float f){
  __bf16 b = (__bf16)f;
  return __builtin_bit_cast(ush, b);
}
__device__ __forceinline__ float lo16f(uint32 w){ return __builtin_bit_cast(float, w << 16); }
__device__ __forceinline__ float hi16f(uint32 w){ return __builtin_bit_cast(float, w & 0xFFFF0000u); }

__device__ __forceinline__ float loadf(const void* p, int i, bool f32){
  return f32 ? ((const float*)p)[i] : bf2f(((const ush*)p)[i]);
}
// raw bf16 fragment load: bit-exact copy of harness weights for bf16 inputs
__device__ __forceinline__ bf16x8 load8bf(const void* p, int i, bool f32){
  bf16x8 r;
  if (!f32){
    uint4 u = *reinterpret_cast<const uint4*>((const ush*)p + i);
    r = __builtin_bit_cast(bf16x8, u);
  } else {
    const float* fp = (const float*)p + i;
    #pragma unroll
    for (int j = 0; j < 8; ++j) r[j] = (__bf16)fp[j];
  }
  return r;
}
__device__ __forceinline__ float ex2(float x){ return __builtin_amdgcn_exp2f(x); }
__device__ __forceinline__ float rcp(float x){ return __builtin_amdgcn_rcpf(x); }

// 7-trans LSTM cell (5 exp + 2 rcp, vs 10 naive): combine the i/f/g rcps into
// one via common denominator, and the o-gate rcp into tanh(c)'s.
//   si=1/A, sf=1/B, tg=(eg-1)/G  (A=1+ei, B=1+ef, G=1+eg)
//   c' = [c*A*G + (eg-1)*B] / (B*A*G);  hv = (ec-1)/((ec+1)*(1+eo))
// Values match the r6 sigm/tnh forms to ~1 ulp; gates ~N(0,1) so all
// intermediates are far from overflow.
__device__ __forceinline__ float cell7(float g0, float g1, float g2, float g3,
                                       float& cc){
  float ei = ex2(-g0 * LOG2E);
  float ef = ex2(-g1 * LOG2E);
  float eg = ex2( g2 * LOG2E2);
  float eo = ex2(-g3 * LOG2E);
  float AG  = (1.0f + ei) * (1.0f + eg);
  float num = cc * AG + (eg - 1.0f) * (1.0f + ef);
  float den = (1.0f + ef) * AG;
  cc = num * rcp(den);
  float ec = ex2(cc * LOG2E2);
  return (ec - 1.0f) * rcp((ec + 1.0f) * (1.0f + eo));
}

__device__ __forceinline__ f32x4 mfma4(const bf16x8* af, const bf16x8* b, f32x4 c){
  f32x4 r = __builtin_amdgcn_mfma_f32_16x16x32_bf16(af[0], b[0], c, 0, 0, 0);
  r = __builtin_amdgcn_mfma_f32_16x16x32_bf16(af[1], b[1], r, 0, 0, 0);
  r = __builtin_amdgcn_mfma_f32_16x16x32_bf16(af[2], b[2], r, 0, 0, 0);
  r = __builtin_amdgcn_mfma_f32_16x16x32_bf16(af[3], b[3], r, 0, 0, 0);
  return r;
}

// 256 blocks x 4 batch rows, 8 waves/block; wave w owns hidden cols [16w,16w+16).
// A-ROW REPLICATION: A[m] = h[m>>2] -> C[4q+r][n] = gates[q][n] in every reg;
// lane (n,q) reads acc[0] directly. Bias rides as the C operand of the first
// MFMA. Pred tile (decoder feedback) = 4 extra MFMAs at the HEAD (rides the
// under-utilized matrix pipe, zero serial-path cost — r8 showed the VALU/DPP
// alternative regresses), COLUMN-REPLICATED B (B[k][n]=wfc[n&1][k]) -> pred
// local + one shfl_xor. Exps interleaved into the MFMA chains at distance 1.
// One barrier per step. 7-trans cell. Preds buffered in LDS, one bulk write.
__global__ void __launch_bounds__(NTHR, 2)
lstm_kernel(const void* __restrict__ xg,  const void* __restrict__ wih,
            const void* __restrict__ whh, const void* __restrict__ bih,
            const void* __restrict__ bhh, const void* __restrict__ wfc,
            const void* __restrict__ bfc, void* __restrict__ outg)
{
  __shared__ __attribute__((aligned(16))) ush x_lds[RB * XSTR];      // [row][t*2+c]
  __shared__ __attribute__((aligned(16))) ush h_lds[2][RB * HSTR];   // [buf][row][j]
  __shared__ __attribute__((aligned(16))) ush pred_lds[RB][PSTR];    // [row][d*2+o]

  const int tid   = threadIdx.x;
  const int lane  = tid & 63;
  const int wv    = tid >> 6;
  const int n     = lane & 15;   // MFMA col index within tile (= A-row m)
  const int q     = lane >> 4;   // quad; this lane's batch row
  const int gbase = wv << 4;
  const int blk   = blockIdx.x;

  // runtime storage-dtype detection (bf16 vs f32) from w_hh bit patterns
  const uint32* wp = (const uint32*)whh;
  int cnt = 0;
  #pragma unroll
  for (int i = 0; i < 64; ++i){
    uint32 e = (wp[i] >> 7) & 0xFFu;
    cnt += (e >= 90u && e <= 140u) ? 1 : 0;
  }
  const bool isf32 = (cnt < 40);

  for (int i = tid; i < 2 * RB * HSTR; i += NTHR) h_lds[0][i] = 0;  // both bufs

  // stage this block's 4 encoder rows into LDS as bf16: [row][t*2+c]
  if (!isf32){
    if (tid < 256){
      int row = tid >> 6, c = (tid & 63) * 8;
      uint4 v = *reinterpret_cast<const uint4*>((const ush*)xg + (blk * RB + row) * (SENC * 2) + c);
      *reinterpret_cast<uint4*>(&x_lds[row * XSTR + c]) = v;
    }
  } else {
    for (int i = tid; i < RB * SENC * 2; i += NTHR){
      int row = i >> 9, c = i & 511;
      x_lds[row * XSTR + c] = f2bf(((const float*)xg)[(blk * RB + row) * (SENC * 2) + c]);
    }
  }

  // ---- loop-invariant preloads: weights RAW (bit-exact for bf16) ----
  float wih0v[4], wih1v[4];
  f32x4 biasC[4];    // broadcast bias, used as C operand of first MFMA
  bf16x8 bfr[4][4];  // [gate p][kk]: B[k][g]=Whh[g][k], k=kk*32+q*8+j, g=p*128+gbase+n
  #pragma unroll
  for (int p = 0; p < 4; ++p){
    int g = p * 128 + gbase + n;
    float b = loadf(bih, g, isf32) + loadf(bhh, g, isf32);
    biasC[p][0] = b; biasC[p][1] = b; biasC[p][2] = b; biasC[p][3] = b;
    wih0v[p] = loadf(wih, g * 2 + 0, isf32);
    wih1v[p] = loadf(wih, g * 2 + 1, isf32);
    #pragma unroll
    for (int kk = 0; kk < 4; ++kk)
      bfr[p][kk] = load8bf(whh, g * HDIM + kk * 32 + q * 8, isf32);
  }
  // pred tile B-frag, COLUMN-REPLICATED: B[k][n] = wfc[n&1][k]
  bf16x8 wfcfr[4];
  #pragma unroll
  for (int kk = 0; kk < 4; ++kk){
    #pragma unroll
    for (int j = 0; j < 8; ++j){
      int k = kk * 32 + q * 8 + j;
      wfcfr[kk][j] = __builtin_bit_cast(__bf16, f2bf(loadf(wfc, (n & 1) * HDIM + k, isf32)));
    }
  }
  f32x4 pbfcC;
  {
    float pb = loadf(bfc, n & 1, isf32);
    pbfcC[0] = pb; pbfcC[1] = pb; pbfcC[2] = pb; pbfcC[3] = pb;
  }
  // per-lane feedback weights: g += wa*pv + wb*po, pv = pred[q][n&1]
  float wav[4], wbv[4];
  #pragma unroll
  for (int p = 0; p < 4; ++p){
    wav[p] = (n & 1) ? wih1v[p] : wih0v[p];
    wbv[p] = (n & 1) ? wih0v[p] : wih1v[p];
  }

  float cc = 0.0f;                   // c-state for (row q, col gbase+n)
  const int arow  = (n >> 2) * HSTR; // replicated A-row base: A[m]=h[m>>2]
  const int hwofs = q * HSTR + gbase + n;  // this lane's h-write offset
  int cur = 0;

  __syncthreads();

  // ---------------- encoder (+ first decode cell at s==SENC) ----------------
  #pragma unroll 1
  for (int s = 0; s <= SENC; ++s){
    int t = (s < SENC) ? s : SENC - 1;   // s==SENC: inp0 = x[:,-1,:]
    uint32 xw = *reinterpret_cast<const uint32*>(&x_lds[q * XSTR + t * 2]);
    float xa = lo16f(xw), xb = hi16f(xw);

    const ush* hb = &h_lds[cur][arow];
    bf16x8 af[4];
    #pragma unroll
    for (int kk = 0; kk < 4; ++kk)
      af[kk] = *reinterpret_cast<const bf16x8*>(hb + kk * 32 + q * 8);

    f32x4 acc0 = mfma4(af, bfr[0], biasC[0]);
    f32x4 acc1 = mfma4(af, bfr[1], biasC[1]);
    float g0 = acc0[0] + wih0v[0] * xa + wih1v[0] * xb;
    float ei = ex2(-g0 * LOG2E);
    f32x4 acc2 = mfma4(af, bfr[2], biasC[2]);
    float g1 = acc1[0] + wih0v[1] * xa + wih1v[1] * xb;
    float ef = ex2(-g1 * LOG2E);
    f32x4 acc3 = mfma4(af, bfr[3], biasC[3]);
    float g2 = acc2[0] + wih0v[2] * xa + wih1v[2] * xb;
    float eg = ex2(g2 * LOG2E2);
    float AG  = (1.0f + ei) * (1.0f + eg);
    float num = cc * AG + (eg - 1.0f) * (1.0f + ef);
    cc = num * rcp((1.0f + ef) * AG);
    float ec = ex2(cc * LOG2E2);
    float g3 = acc3[0] + wih0v[3] * xa + wih1v[3] * xb;
    float eo = ex2(-g3 * LOG2E);
    float hv = (ec - 1.0f) * rcp((ec + 1.0f) * (1.0f + eo));
    h_lds[cur ^ 1][hwofs] = f2bf_hw(hv);

    __syncthreads();
    cur ^= 1;
  }

  // ---------------- decoder: pure h-recurrence + pred feedback --------------
  #pragma unroll 1
  for (int d = 0; d < TDEC - 1; ++d){
    const ush* hb = &h_lds[cur][arow];
    bf16x8 af[4];
    #pragma unroll
    for (int kk = 0; kk < 4; ++kk)
      af[kk] = *reinterpret_cast<const bf16x8*>(hb + kk * 32 + q * 8);

    // pred_d: every lane gets pred[q][n&1] locally (column-replicated B)
    f32x4 a4 = mfma4(af, wfcfr, pbfcC);
    float pv = a4[0];
    float po = __shfl_xor(pv, 1, 64);      // partner column

    f32x4 acc0 = mfma4(af, bfr[0], biasC[0]);
    f32x4 acc1 = mfma4(af, bfr[1], biasC[1]);
    float g0 = acc0[0] + wav[0] * pv + wbv[0] * po;
    float ei = ex2(-g0 * LOG2E);
    f32x4 acc2 = mfma4(af, bfr[2], biasC[2]);
    float g1 = acc1[0] + wav[1] * pv + wbv[1] * po;
    float ef = ex2(-g1 * LOG2E);
    f32x4 acc3 = mfma4(af, bfr[3], biasC[3]);
    float g2 = acc2[0] + wav[2] * pv + wbv[2] * po;
    float eg = ex2(g2 * LOG2E2);
    float AG  = (1.0f + ei) * (1.0f + eg);
    float num = cc * AG + (eg - 1.0f) * (1.0f + ef);
    cc = num * rcp((1.0f + ef) * AG);
    float ec = ex2(cc * LOG2E2);
    float g3 = acc3[0] + wav[3] * pv + wbv[3] * po;
    float eo = ex2(-g3 * LOG2E);
    float hv = (ec - 1.0f) * rcp((ec + 1.0f) * (1.0f + eo));
    h_lds[cur ^ 1][hwofs] = f2bf_hw(hv);

    if (wv == 0 && n < 2)
      pred_lds[q][d * 2 + n] = f2bf_hw(pv);   // n&1==n for n<2

    __syncthreads();
    cur ^= 1;
  }

  // epilogue: pred_511 from final h (h_lds[cur])
  if (wv == 0){
    const ush* hb = &h_lds[cur][arow];
    bf16x8 af[4];
    #pragma unroll
    for (int kk = 0; kk < 4; ++kk)
      af[kk] = *reinterpret_cast<const bf16x8*>(hb + kk * 32 + q * 8);
    f32x4 a4 = mfma4(af, wfcfr, pbfcC);
    if (n < 2)
      pred_lds[q][(TDEC - 1) * 2 + n] = f2bf_hw(a4[0]);
  }
  __syncthreads();

  // bulk coalesced output write: 4 rows x 1024 ush per block
  if (!isf32){
    int row = tid >> 7, c = (tid & 127) * 8;  // 512 threads x uint4
    uint4 v = *reinterpret_cast<const uint4*>(&pred_lds[row][c]);
    *reinterpret_cast<uint4*>((ush*)outg + (blk * RB + row) * (TDEC * 2) + c) = v;
  } else {
    for (int i = tid; i < RB * TDEC * 2; i += NTHR){
      int row = i >> 10, c = i & 1023;
      ((float*)outg)[(blk * RB + row) * (TDEC * 2) + c] = bf2f(pred_lds[row][c]);
    }
  }
}

extern "C" void kernel_launch(void* const* d_in, const int* in_sizes, int n_in,
                              void* d_out, int out_size, void* d_ws, size_t ws_size,
                              hipStream_t stream) {
  lstm_kernel<<<dim3(NBLK), dim3(NTHR), 0, stream>>>(
      d_in[0], d_in[1], d_in[2], d_in[3], d_in[4], d_in[5], d_in[6], d_out);
}

// Round 10
// 432.891 us; speedup vs baseline: 1.1870x; 1.0260x over previous
//
#include <hip/hip_runtime.h>

typedef unsigned short ush;
typedef unsigned int uint32;
typedef __attribute__((ext_vector_type(8))) __bf16 bf16x8;
typedef __attribute__((ext_vector_type(4))) float f32x4;

#define NBLK 256
#define RB   4     // batch rows per block
#define NTHR 512
#define SENC 256
#define TDEC 512
#define HDIM 128
#define HSTR 144   // h row stride (ush): 72 dw ≡ 8 mod 32 -> replicated reads/writes 2-way (free)
#define XSTR 520   // x row stride (ush)
#define PSTR 1024  // pred row stride (ush)

#define LOG2E  1.4426950408889634f
#define LOG2E2 2.8853900817779268f

__device__ __forceinline__ float bf2f(ush u){
  uint32 v = ((uint32)u) << 16;
  return __builtin_bit_cast(float, v);
}
__device__ __forceinline__ ush f2bf(float f){            // RNE (manual; preload path)
  uint32 u = __builtin_bit_cast(uint32, f);
  u = (u + 0x7FFFu + ((u >> 16) & 1u)) >> 16;
  return (ush)u;
}
// hot-path RNE convert: single v_cvt op on gfx950, same rounding as f2bf
__device__ __forceinline__ ush f2bf_hw(float f){
  __bf16 b = (__bf16)f;
  return __builtin_bit_cast(ush, b);
}
__device__ __forceinline__ float lo16f(uint32 w){ return __builtin_bit_cast(float, w << 16); }
__device__ __forceinline__ float hi16f(uint32 w){ return __builtin_bit_cast(float, w & 0xFFFF0000u); }

__device__ __forceinline__ float loadf(const void* p, int i, bool f32){
  return f32 ? ((const float*)p)[i] : bf2f(((const ush*)p)[i]);
}
// raw bf16 fragment load: bit-exact copy of harness weights for bf16 inputs
__device__ __forceinline__ bf16x8 load8bf(const void* p, int i, bool f32){
  bf16x8 r;
  if (!f32){
    uint4 u = *reinterpret_cast<const uint4*>((const ush*)p + i);
    r = __builtin_bit_cast(bf16x8, u);
  } else {
    const float* fp = (const float*)p + i;
    #pragma unroll
    for (int j = 0; j < 8; ++j) r[j] = (__bf16)fp[j];
  }
  return r;
}
__device__ __forceinline__ float ex2(float x){ return __builtin_amdgcn_exp2f(x); }
__device__ __forceinline__ float rcp(float x){ return __builtin_amdgcn_rcpf(x); }

// lane <-> lane^1 swap via DPP quad_perm [1,0,3,2]: full-rate VALU op
// (vs __shfl_xor's ds_swizzle on the LDS pipe). Bit-identical data motion.
__device__ __forceinline__ float dpp_swap1(float x){
  int yi = __builtin_amdgcn_update_dpp(0, __builtin_bit_cast(int, x),
                                       0xB1, 0xF, 0xF, true);
  return __builtin_bit_cast(float, yi);
}

__device__ __forceinline__ f32x4 mfma4(const bf16x8* af, const bf16x8* b, f32x4 c){
  f32x4 r = __builtin_amdgcn_mfma_f32_16x16x32_bf16(af[0], b[0], c, 0, 0, 0);
  r = __builtin_amdgcn_mfma_f32_16x16x32_bf16(af[1], b[1], r, 0, 0, 0);
  r = __builtin_amdgcn_mfma_f32_16x16x32_bf16(af[2], b[2], r, 0, 0, 0);
  r = __builtin_amdgcn_mfma_f32_16x16x32_bf16(af[3], b[3], r, 0, 0, 0);
  return r;
}

// 256 blocks x 4 batch rows, 8 waves/block; wave w owns hidden cols [16w,16w+16).
// A-ROW REPLICATION: A[m] = h[m>>2] -> C[4q+r][n] = gates[q][n] in every reg;
// lane (n,q) reads acc[0] directly. Bias rides as the C operand of the first
// MFMA. Pred tile (decoder feedback) = 4 extra MFMAs at the HEAD (rides the
// matrix pipe, zero serial-path cost), COLUMN-REPLICATED B (B[k][n]=wfc[n&1][k])
// -> pred local + one DPP quad-swap for the partner column. Exps interleaved
// into the MFMA chains at distance 1. 7-trans cell (5 exp + 2 rcp). One
// barrier per step. Preds buffered in LDS, one bulk coalesced write.
// Structural notes (falsified levers — do not retry): s_setprio stagger (r7,
// arbitration is round-robin), DPP/VALU pred offload (r8, lengthens serial
// path), any (RB, blocks/CU) re-tiling (active-SIMDs x tile-efficiency is
// constant = 64 effective CUs for B=1024).
__global__ void __launch_bounds__(NTHR, 2)
lstm_kernel(const void* __restrict__ xg,  const void* __restrict__ wih,
            const void* __restrict__ whh, const void* __restrict__ bih,
            const void* __restrict__ bhh, const void* __restrict__ wfc,
            const void* __restrict__ bfc, void* __restrict__ outg)
{
  __shared__ __attribute__((aligned(16))) ush x_lds[RB * XSTR];      // [row][t*2+c]
  __shared__ __attribute__((aligned(16))) ush h_lds[2][RB * HSTR];   // [buf][row][j]
  __shared__ __attribute__((aligned(16))) ush pred_lds[RB][PSTR];    // [row][d*2+o]

  const int tid   = threadIdx.x;
  const int lane  = tid & 63;
  const int wv    = tid >> 6;
  const int n     = lane & 15;   // MFMA col index within tile (= A-row m)
  const int q     = lane >> 4;   // quad; this lane's batch row
  const int gbase = wv << 4;
  const int blk   = blockIdx.x;

  // runtime storage-dtype detection (bf16 vs f32) from w_hh bit patterns
  const uint32* wp = (const uint32*)whh;
  int cnt = 0;
  #pragma unroll
  for (int i = 0; i < 64; ++i){
    uint32 e = (wp[i] >> 7) & 0xFFu;
    cnt += (e >= 90u && e <= 140u) ? 1 : 0;
  }
  const bool isf32 = (cnt < 40);

  for (int i = tid; i < 2 * RB * HSTR; i += NTHR) h_lds[0][i] = 0;  // both bufs

  // stage this block's 4 encoder rows into LDS as bf16: [row][t*2+c]
  if (!isf32){
    if (tid < 256){
      int row = tid >> 6, c = (tid & 63) * 8;
      uint4 v = *reinterpret_cast<const uint4*>((const ush*)xg + (blk * RB + row) * (SENC * 2) + c);
      *reinterpret_cast<uint4*>(&x_lds[row * XSTR + c]) = v;
    }
  } else {
    for (int i = tid; i < RB * SENC * 2; i += NTHR){
      int row = i >> 9, c = i & 511;
      x_lds[row * XSTR + c] = f2bf(((const float*)xg)[(blk * RB + row) * (SENC * 2) + c]);
    }
  }

  // ---- loop-invariant preloads: weights RAW (bit-exact for bf16) ----
  float wih0v[4], wih1v[4];
  f32x4 biasC[4];    // broadcast bias, used as C operand of first MFMA
  bf16x8 bfr[4][4];  // [gate p][kk]: B[k][g]=Whh[g][k], k=kk*32+q*8+j, g=p*128+gbase+n
  #pragma unroll
  for (int p = 0; p < 4; ++p){
    int g = p * 128 + gbase + n;
    float b = loadf(bih, g, isf32) + loadf(bhh, g, isf32);
    biasC[p][0] = b; biasC[p][1] = b; biasC[p][2] = b; biasC[p][3] = b;
    wih0v[p] = loadf(wih, g * 2 + 0, isf32);
    wih1v[p] = loadf(wih, g * 2 + 1, isf32);
    #pragma unroll
    for (int kk = 0; kk < 4; ++kk)
      bfr[p][kk] = load8bf(whh, g * HDIM + kk * 32 + q * 8, isf32);
  }
  // pred tile B-frag, COLUMN-REPLICATED: B[k][n] = wfc[n&1][k]
  bf16x8 wfcfr[4];
  #pragma unroll
  for (int kk = 0; kk < 4; ++kk){
    #pragma unroll
    for (int j = 0; j < 8; ++j){
      int k = kk * 32 + q * 8 + j;
      wfcfr[kk][j] = __builtin_bit_cast(__bf16, f2bf(loadf(wfc, (n & 1) * HDIM + k, isf32)));
    }
  }
  f32x4 pbfcC;
  {
    float pb = loadf(bfc, n & 1, isf32);
    pbfcC[0] = pb; pbfcC[1] = pb; pbfcC[2] = pb; pbfcC[3] = pb;
  }
  // per-lane feedback weights: g += wa*pv + wb*po, pv = pred[q][n&1]
  float wav[4], wbv[4];
  #pragma unroll
  for (int p = 0; p < 4; ++p){
    wav[p] = (n & 1) ? wih1v[p] : wih0v[p];
    wbv[p] = (n & 1) ? wih0v[p] : wih1v[p];
  }

  float cc = 0.0f;                   // c-state for (row q, col gbase+n)
  const int arow  = (n >> 2) * HSTR; // replicated A-row base: A[m]=h[m>>2]
  const int hwofs = q * HSTR + gbase + n;  // this lane's h-write offset
  int cur = 0;

  __syncthreads();

  // ---------------- encoder (+ first decode cell at s==SENC) ----------------
  #pragma unroll 1
  for (int s = 0; s <= SENC; ++s){
    int t = (s < SENC) ? s : SENC - 1;   // s==SENC: inp0 = x[:,-1,:]
    uint32 xw = *reinterpret_cast<const uint32*>(&x_lds[q * XSTR + t * 2]);
    float xa = lo16f(xw), xb = hi16f(xw);

    const ush* hb = &h_lds[cur][arow];
    bf16x8 af[4];
    #pragma unroll
    for (int kk = 0; kk < 4; ++kk)
      af[kk] = *reinterpret_cast<const bf16x8*>(hb + kk * 32 + q * 8);

    f32x4 acc0 = mfma4(af, bfr[0], biasC[0]);
    f32x4 acc1 = mfma4(af, bfr[1], biasC[1]);
    float g0 = acc0[0] + wih0v[0] * xa + wih1v[0] * xb;
    float ei = ex2(-g0 * LOG2E);
    f32x4 acc2 = mfma4(af, bfr[2], biasC[2]);
    float g1 = acc1[0] + wih0v[1] * xa + wih1v[1] * xb;
    float ef = ex2(-g1 * LOG2E);
    f32x4 acc3 = mfma4(af, bfr[3], biasC[3]);
    float g2 = acc2[0] + wih0v[2] * xa + wih1v[2] * xb;
    float eg = ex2(g2 * LOG2E2);
    float AG  = (1.0f + ei) * (1.0f + eg);
    float num = cc * AG + (eg - 1.0f) * (1.0f + ef);
    cc = num * rcp((1.0f + ef) * AG);
    float ec = ex2(cc * LOG2E2);
    float g3 = acc3[0] + wih0v[3] * xa + wih1v[3] * xb;
    float eo = ex2(-g3 * LOG2E);
    float hv = (ec - 1.0f) * rcp((ec + 1.0f) * (1.0f + eo));
    h_lds[cur ^ 1][hwofs] = f2bf_hw(hv);

    __syncthreads();
    cur ^= 1;
  }

  // ---------------- decoder: pure h-recurrence + pred feedback --------------
  #pragma unroll 1
  for (int d = 0; d < TDEC - 1; ++d){
    const ush* hb = &h_lds[cur][arow];
    bf16x8 af[4];
    #pragma unroll
    for (int kk = 0; kk < 4; ++kk)
      af[kk] = *reinterpret_cast<const bf16x8*>(hb + kk * 32 + q * 8);

    // pred_d: every lane gets pred[q][n&1] locally (column-replicated B)
    f32x4 a4 = mfma4(af, wfcfr, pbfcC);
    float pv = a4[0];
    float po = dpp_swap1(pv);              // partner column, full-rate VALU

    f32x4 acc0 = mfma4(af, bfr[0], biasC[0]);
    f32x4 acc1 = mfma4(af, bfr[1], biasC[1]);
    float g0 = acc0[0] + wav[0] * pv + wbv[0] * po;
    float ei = ex2(-g0 * LOG2E);
    f32x4 acc2 = mfma4(af, bfr[2], biasC[2]);
    float g1 = acc1[0] + wav[1] * pv + wbv[1] * po;
    float ef = ex2(-g1 * LOG2E);
    f32x4 acc3 = mfma4(af, bfr[3], biasC[3]);
    float g2 = acc2[0] + wav[2] * pv + wbv[2] * po;
    float eg = ex2(g2 * LOG2E2);
    float AG  = (1.0f + ei) * (1.0f + eg);
    float num = cc * AG + (eg - 1.0f) * (1.0f + ef);
    cc = num * rcp((1.0f + ef) * AG);
    float ec = ex2(cc * LOG2E2);
    float g3 = acc3[0] + wav[3] * pv + wbv[3] * po;
    float eo = ex2(-g3 * LOG2E);
    float hv = (ec - 1.0f) * rcp((ec + 1.0f) * (1.0f + eo));
    h_lds[cur ^ 1][hwofs] = f2bf_hw(hv);

    if (wv == 0 && n < 2)
      pred_lds[q][d * 2 + n] = f2bf_hw(pv);   // n&1==n for n<2

    __syncthreads();
    cur ^= 1;
  }

  // epilogue: pred_511 from final h (h_lds[cur])
  if (wv == 0){
    const ush* hb = &h_lds[cur][arow];
    bf16x8 af[4];
    #pragma unroll
    for (int kk = 0; kk < 4; ++kk)
      af[kk] = *reinterpret_cast<const bf16x8*>(hb + kk * 32 + q * 8);
    f32x4 a4 = mfma4(af, wfcfr, pbfcC);
    if (n < 2)
      pred_lds[q][(TDEC - 1) * 2 + n] = f2bf_hw(a4[0]);
  }
  __syncthreads();

  // bulk coalesced output write: 4 rows x 1024 ush per block
  if (!isf32){
    int row = tid >> 7, c = (tid & 127) * 8;  // 512 threads x uint4
    uint4 v = *reinterpret_cast<const uint4*>(&pred_lds[row][c]);
    *reinterpret_cast<uint4*>((ush*)outg + (blk * RB + row) * (TDEC * 2) + c) = v;
  } else {
    for (int i = tid; i < RB * TDEC * 2; i += NTHR){
      int row = i >> 10, c = i & 1023;
      ((float*)outg)[(blk * RB + row) * (TDEC * 2) + c] = bf2f(pred_lds[row][c]);
    }
  }
}

extern "C" void kernel_launch(void* const* d_in, const int* in_sizes, int n_in,
                              void* d_out, int out_size, void* d_ws, size_t ws_size,
                              hipStream_t stream) {
  lstm_kernel<<<dim3(NBLK), dim3(NTHR), 0, stream>>>(
      d_in[0], d_in[1], d_in[2], d_in[3], d_in[4], d_in[5], d_in[6], d_out);
}